// Round 5
// baseline (123.417 us; speedup 1.0000x reference)
//
#include <hip/hip_runtime.h>
#include <hip/hip_bf16.h>
#include <cstdint>

// Problem constants
#define SDIM 160
#define HDIM 768
#define HALF 384
#define ODIM 260
#define OPAD 272           // 17 * 16
#define CHUNK_BYTES 34816  // 8 kgroups * 272 rows * 16B (W2b chunk)
// Workspace layout (bytes): pad@0(16) yb@16 Lb@245776 Rt@491536 W2b@737296
//                           W1b@1155088 end@3514384
#define WS_SMALL 1155088
#define WS_BIG   3514384

typedef __attribute__((ext_vector_type(8))) short short8;
typedef __attribute__((ext_vector_type(4))) float floatx4;
typedef _Float16 half8 __attribute__((ext_vector_type(8)));

typedef const __attribute__((address_space(1))) unsigned char gl_u8;
typedef __attribute__((address_space(3))) unsigned char lds_u8;

static __device__ __forceinline__ float bf2f(unsigned short u) {
    union { unsigned int i; float f; } v; v.i = ((unsigned int)u) << 16; return v.f;
}
static __device__ __forceinline__ unsigned short f2bf(float x) {
    __hip_bfloat16 h = __float2bfloat16(x);
    return *reinterpret_cast<unsigned short*>(&h);
}
static __device__ __forceinline__ unsigned short f2h(float x) {
    _Float16 h = (_Float16)x;
    return *reinterpret_cast<unsigned short*>(&h);
}
static __device__ __forceinline__ float q(float x) { return bf2f(f2bf(x)); }

// ---------------------------------------------------------------------------
// Kernel 1: RoPE(y) -> yb bf16; W2 -> W2b f16 [kg96][row272][8] (pad rows 0);
// (big path) W1 -> W1b bf16 [kg96][row1536][8] (row<768 = L-half, >=768 = R).
// R17: transpose mappings ROW-FASTEST -> coalesced 16B stores (proven good).
// ---------------------------------------------------------------------------
__global__ __launch_bounds__(256) void prep_kernel(
    const float* __restrict__ y, const float* __restrict__ W1,
    const float* __restrict__ W2,
    unsigned short* __restrict__ yb, unsigned short* __restrict__ W2b,
    unsigned short* __restrict__ W1b, int do_w1b) {
    int bid = blockIdx.x;
    int t = threadIdx.x;
    if (bid < SDIM) {
        int s = bid;
        for (int p = t; p < HALF; p += 256) {
            float invf = __expf(-(2.0f * (float)p / (float)HDIM) * 9.210340371976184f);
            float th = (float)s * invf;
            float c = cosf(th), sn = sinf(th);
            float y0 = y[s * HDIM + 2 * p], y1 = y[s * HDIM + 2 * p + 1];
            yb[s * HDIM + 2 * p]     = f2bf(y0 * c - y1 * sn);
            yb[s * HDIM + 2 * p + 1] = f2bf(y1 * c + y0 * sn);
        }
    } else if (bid < SDIM + 102) {
        int idx = (bid - SDIM) * 256 + t;       // [0, 96*272)
        if (idx < 96 * OPAD) {
            int kg = idx / OPAD, row = idx - kg * OPAD;  // row fastest
            unsigned short o8[8];
            if (row < ODIM) {
                float4 a = *reinterpret_cast<const float4*>(W2 + row * HDIM + kg * 8);
                float4 b = *reinterpret_cast<const float4*>(W2 + row * HDIM + kg * 8 + 4);
                o8[0] = f2h(a.x); o8[1] = f2h(a.y); o8[2] = f2h(a.z); o8[3] = f2h(a.w);
                o8[4] = f2h(b.x); o8[5] = f2h(b.y); o8[6] = f2h(b.z); o8[7] = f2h(b.w);
            } else {
                #pragma unroll
                for (int e = 0; e < 8; ++e) o8[e] = 0;
            }
            *reinterpret_cast<uint4*>(W2b + ((size_t)kg * OPAD + row) * 8) =
                *reinterpret_cast<uint4*>(o8);
        }
    } else if (do_w1b) {
        int idx = (bid - SDIM - 102) * 256 + t; // [0, 96*1536)
        int kg = idx / 1536, row = idx - kg * 1536;      // row fastest
        const float* src = (row < 768) ? (W1 + row * 1536 + kg * 8)
                                       : (W1 + (row - 768) * 1536 + 768 + kg * 8);
        float4 a = *reinterpret_cast<const float4*>(src);
        float4 b = *reinterpret_cast<const float4*>(src + 4);
        unsigned short o8[8];
        o8[0] = f2bf(a.x); o8[1] = f2bf(a.y); o8[2] = f2bf(a.z); o8[3] = f2bf(a.w);
        o8[4] = f2bf(b.x); o8[5] = f2bf(b.y); o8[6] = f2bf(b.z); o8[7] = f2bf(b.w);
        *reinterpret_cast<uint4*>(W1b + ((size_t)kg * 1536 + row) * 8) =
            *reinterpret_cast<uint4*>(o8);
    }
}

// ---------------------------------------------------------------------------
// Kernel 2 (lr4, R19, proven): barrier-free L/R GEMM from W1b (L2-resident).
// Grid (96,10): one 16-row s-tile per wave, 960 waves (~3.75/CU) -- this
// kernel is latency-bound; wave count is the latency-hiding resource.
// ---------------------------------------------------------------------------
__global__ __launch_bounds__(64, 2) void lr3_kernel(
    const unsigned short* __restrict__ yb, const unsigned short* __restrict__ W1b,
    const float* __restrict__ b1,
    unsigned short* __restrict__ Lb, unsigned short* __restrict__ Rt) {
    int l = threadIdx.x & 63;
    int l16 = l & 15, qd = l >> 4;
    int mt = blockIdx.x;                 // m-tile [0,96)
    int sq = blockIdx.y;                 // s-tile [0,10)
    int s0 = sq * 16 + l16;

    floatx4 acc = (floatx4){0.0f, 0.0f, 0.0f, 0.0f};

    const unsigned short* yrow0 = yb + s0 * HDIM;

    for (int ks = 0; ks < 24; ++ks) {
        int k = ks * 32 + qd * 8;
        int kg = ks * 4 + qd;
        union { uint4 u; short8 s; } bu0, au;
        bu0.u = *reinterpret_cast<const uint4*>(yrow0 + k);
        au.u = *reinterpret_cast<const uint4*>(
            W1b + ((size_t)kg * 1536 + mt * 16 + l16) * 8);
        acc = __builtin_amdgcn_mfma_f32_16x16x32_bf16(
            au.s, bu0.s, acc, 0, 0, 0);
    }

    int o2 = mt * 16 + qd * 4;
    int s_out = sq * 16 + l16;
    unsigned short out4[4];
    if (o2 < 768) {
        #pragma unroll
        for (int r = 0; r < 4; ++r) out4[r] = f2h(acc[r]);
        *reinterpret_cast<uint2*>(Lb + s_out * HDIM + o2) =
            *reinterpret_cast<uint2*>(out4);
    } else {
        int ob = o2 - 768;               // [0,768), aligned to 4
        #pragma unroll
        for (int r = 0; r < 4; ++r)
            out4[r] = f2h(acc[r] + b1[ob + r]);
        // Rt[kg=ob>>3][s][e=ob&7], 4 consecutive e -> uint2 store
        *reinterpret_cast<uint2*>(
            Rt + ((size_t)(ob >> 3) * SDIM + s_out) * 8 + (ob & 7)) =
            *reinterpret_cast<uint2*>(out4);
    }
}

// ---------------------------------------------------------------------------
// Kernel 3 (small-ws path only): pure-VALU L/R (f16; R transposed).
// ---------------------------------------------------------------------------
__global__ __launch_bounds__(256) void lr_fallback_kernel(
    const unsigned short* __restrict__ yb, const float* __restrict__ W1,
    const float* __restrict__ b1,
    unsigned short* __restrict__ Lb, unsigned short* __restrict__ Rt) {
    int idx = blockIdx.x * 256 + threadIdx.x;   // [0, 160*1536)
    int s = idx / 1536;
    int o2 = idx - s * 1536;
    const unsigned short* yrow = yb + s * HDIM;
    if (o2 < 768) {
        const float* wp = W1 + o2 * 1536;
        float a0 = 0.0f;
        for (int k = 0; k < HDIM; ++k) a0 += q(wp[k]) * bf2f(yrow[k]);
        Lb[s * HDIM + o2] = f2h(a0);
    } else {
        int ob = o2 - 768;
        const float* wp = W1 + ob * 1536 + 768;
        float a0 = 0.0f;
        for (int k = 0; k < HDIM; ++k) a0 += q(wp[k]) * bf2f(yrow[k]);
        Rt[((size_t)(ob >> 3) * SDIM + s) * 8 + (ob & 7)] = f2h(a0 + b1[ob]);
    }
}

// ---------------------------------------------------------------------------
// Kernel 4 (R20): f16 pair-GEMM with COUNTED-VMCNT triple-buffer pipeline.
// Same wave layout / tile / staged bytes / compute order as the proven r14
// shape (2 i x 32 j, 8 waves, grid (80,5)). CHANGE: 2 -> 3 LDS buffers
// (104 KB), prefetch depth 2, raw s_barrier + per-wave counted
// s_waitcnt vmcnt(n_w) instead of __syncthreads' full vmcnt(0) drain
// (guide T4 / m97 stall pattern: the compiler's vmcnt(0)-before-barrier
// drains the prefetch queue 12x per block).
// Invariant at top of iter kc: outstanding = chunks {kc, kc+1}; vmcnt(n_w)
// retires the oldest n_w = chunk kc (FIFO semantics, m135). n_w = 5 for
// waves 0-1, 4 for waves 2-7 (seg = w + it*8 < 34). kc==11 waits vmcnt(0).
// Buffer safety: bufs kc, kc+1, kc+2 mod 3 distinct; STAGE(kc+2) overwrites
// buf (kc-1)%3 only after the barrier confirming all waves finished iter
// kc-1. Barrier count unchanged (1/iter). Output bit-identical.
// HISTORY: r15 m-split regressed (125.2); R18 i-tile 4x regressed (113.3)
// -> main is NOT LDS-read/L2-BW/VALU-bound; this targets the drain stall.
// ---------------------------------------------------------------------------
__global__ __launch_bounds__(512) void main_kernel(
    const unsigned short* __restrict__ Lb, const unsigned short* __restrict__ Rt,
    const unsigned short* __restrict__ W2b,
    const float* __restrict__ b2, float* __restrict__ out) {
    __shared__ __align__(16) unsigned char lds[3 * CHUNK_BYTES];

    int w = threadIdx.x >> 6;        // 0..7
    int l = threadIdx.x & 63;
    int l16 = l & 15, qd = l >> 4;
    int jh = w & 1;                  // j-half
    int mq = w >> 1;                 // m-quarter
    int mt0 = mq * 4;
    int nmt = (mq == 3) ? 5 : 4;     // m-split 4/4/4/5 (17 tiles)
    int i0 = blockIdx.x * 2;
    int j = blockIdx.y * 32 + jh * 16 + l16;

    floatx4 acc[2][5];
    #pragma unroll
    for (int c = 0; c < 2; ++c)
        #pragma unroll
        for (int mtl = 0; mtl < 5; ++mtl)
            acc[c][mtl] = (floatx4){0.0f, 0.0f, 0.0f, 0.0f};

    const unsigned short* Lrow0 = Lb + i0 * HDIM;
    const unsigned short* Lrow1 = Lb + (i0 + 1) * HDIM;
    const unsigned char* wsrc = reinterpret_cast<const unsigned char*>(W2b);

    // Stage chunk 'ch' into buffer ch%3. Wave w: segments w, w+8, ... (<34).
    auto STAGE = [&](int ch) {
        const unsigned char* gsrc = wsrc + ch * CHUNK_BYTES;
        unsigned char* ldst = lds + (ch % 3) * CHUNK_BYTES;
        #pragma unroll
        for (int it = 0; it < 5; ++it) {
            int seg = w + it * 8;
            if (seg < 34) {
                __builtin_amdgcn_global_load_lds(
                    (gl_u8*)(gsrc + seg * 1024 + l * 16),
                    (lds_u8*)(ldst + seg * 1024), 16, 0, 0);
            }
        }
    };

    STAGE(0);
    STAGE(1);

    for (int kc = 0; kc < 12; ++kc) {
        // Wait for chunk kc's loads (own-wave count), then barrier so every
        // wave's chunk-kc segments are visible in LDS. Never vmcnt(0) in the
        // steady state -- chunk kc+1's loads stay in flight across the
        // barrier (T4).
        if (kc == 11) {
            asm volatile("s_waitcnt vmcnt(0)" ::: "memory");
        } else if (w < 2) {
            asm volatile("s_waitcnt vmcnt(5)" ::: "memory");
        } else {
            asm volatile("s_waitcnt vmcnt(4)" ::: "memory");
        }
        __builtin_amdgcn_s_barrier();
        // Prefetch chunk kc+2 into buf (kc+2)%3 (= (kc-1)%3, whose readers
        // all passed the barrier above).
        if (kc < 10) STAGE(kc + 2);

        int bufbase = (kc % 3) * CHUNK_BYTES;
        #pragma unroll
        for (int ks = 0; ks < 2; ++ks) {
            int k = kc * 64 + ks * 32 + qd * 8;
            int kg = kc * 8 + ks * 4 + qd;
            half8 bfrag[2];
            // R read: contiguous across lanes (Rt[kg][j][8])
            union { uint4 u; half8 h; } ru;
            ru.u = *reinterpret_cast<const uint4*>(
                Rt + ((size_t)kg * SDIM + j) * 8);
            #pragma unroll
            for (int c = 0; c < 2; ++c) {
                const unsigned short* Lr = c ? Lrow1 : Lrow0;
                union { uint4 u; half8 h; } lu;
                lu.u = *reinterpret_cast<const uint4*>(Lr + k);
                half8 hv = lu.h + ru.h;          // v_pk_add_f16
                #pragma unroll
                for (int e = 0; e < 8; ++e)      // v_pk_max_f16
                    hv[e] = hv[e] > (_Float16)0.0f ? hv[e] : (_Float16)0.0f;
                bfrag[c] = hv;
            }
            int ldsbase = bufbase + ((ks * 4 + qd) * OPAD + l16) * 16;
            #pragma unroll
            for (int mtl = 0; mtl < 5; ++mtl) {
                if (mtl < nmt) {
                    union { uint4 u; half8 h; } au;
                    au.u = *reinterpret_cast<const uint4*>(
                        lds + ldsbase + (mt0 + mtl) * 256);
                    acc[0][mtl] = __builtin_amdgcn_mfma_f32_16x16x32_f16(
                        au.h, bfrag[0], acc[0][mtl], 0, 0, 0);
                    acc[1][mtl] = __builtin_amdgcn_mfma_f32_16x16x32_f16(
                        au.h, bfrag[1], acc[1][mtl], 0, 0, 0);
                }
            }
        }
    }

    #pragma unroll
    for (int c = 0; c < 2; ++c) {
        int i = i0 + c;
        #pragma unroll
        for (int mtl = 0; mtl < 5; ++mtl) {
            if (mtl < nmt) {
                int ob = (mt0 + mtl) * 16 + qd * 4;
                if (ob < ODIM) {
                    float4 bv = *reinterpret_cast<const float4*>(b2 + ob);
                    int rel = ob >> 2;
                    float4 v;
                    v.x = 1.0f / (1.0f + __expf(-(acc[c][mtl][0] + bv.x)));
                    v.y = 1.0f / (1.0f + __expf(-(acc[c][mtl][1] + bv.y)));
                    v.z = 1.0f / (1.0f + __expf(-(acc[c][mtl][2] + bv.z)));
                    v.w = 1.0f / (1.0f + __expf(-(acc[c][mtl][3] + bv.w)));
                    *reinterpret_cast<float4*>(
                        out + (((rel * SDIM) + i) * SDIM + j) * 4) = v;
                }
            }
        }
    }
}

__global__ void ws_too_small_kernel(float* out) { out[0] = 999.0f; }

extern "C" void kernel_launch(void* const* d_in, const int* in_sizes, int n_in,
                              void* d_out, int out_size, void* d_ws, size_t ws_size,
                              hipStream_t stream) {
    const float* y  = (const float*)d_in[0];
    // d_in[1] = event_idx : unused by the reference
    const float* W1 = (const float*)d_in[2];
    const float* b1 = (const float*)d_in[3];
    const float* W2 = (const float*)d_in[4];
    const float* b2 = (const float*)d_in[5];
    float* out = (float*)d_out;

    if (ws_size < (size_t)WS_SMALL) {
        ws_too_small_kernel<<<dim3(1), dim3(1), 0, stream>>>(out);
        return;
    }

    unsigned short* yb  = (unsigned short*)((char*)d_ws + 16);    // 160*768
    unsigned short* Lb  = yb + SDIM * HDIM;
    unsigned short* Rt  = Lb + SDIM * HDIM;                       // 96*160*8
    unsigned short* W2b = Rt + SDIM * HDIM;                       // 96*272*8
    unsigned short* W1b = W2b + 96 * OPAD * 8;                    // 96*1536*8

    if (ws_size >= (size_t)WS_BIG) {
        prep_kernel<<<dim3(SDIM + 102 + 576), dim3(256), 0, stream>>>(
            y, W1, W2, yb, W2b, W1b, 1);
        lr3_kernel<<<dim3(96, 10), dim3(64), 0, stream>>>(yb, W1b, b1, Lb, Rt);
        main_kernel<<<dim3(80, 5), dim3(512), 0, stream>>>(Lb, Rt, W2b, b2, out);
    } else {
        prep_kernel<<<dim3(SDIM + 102), dim3(256), 0, stream>>>(
            y, W1, W2, yb, W2b, W1b, 0);
        lr_fallback_kernel<<<dim3(960), dim3(256), 0, stream>>>(yb, W1, b1, Lb, Rt);
        main_kernel<<<dim3(80, 5), dim3(512), 0, stream>>>(Lb, Rt, W2b, b2, out);
    }
}

// Round 6
// 122.697 us; speedup vs baseline: 1.0059x; 1.0059x over previous
//
#include <hip/hip_runtime.h>
#include <hip/hip_bf16.h>
#include <cstdint>

// Problem constants
#define SDIM 160
#define HDIM 768
#define HALF 384
#define ODIM 260
#define OPAD 272           // 17 * 16
// Workspace layout (bytes): pad@0(16) yb@16 Lb@245776 Rt@491536 W2b@737296
//                           W1b@1155088 end@3514384
#define WS_SMALL 1155088
#define WS_BIG   3514384

typedef __attribute__((ext_vector_type(8))) short short8;
typedef __attribute__((ext_vector_type(4))) float floatx4;
typedef _Float16 half8 __attribute__((ext_vector_type(8)));

static __device__ __forceinline__ float bf2f(unsigned short u) {
    union { unsigned int i; float f; } v; v.i = ((unsigned int)u) << 16; return v.f;
}
static __device__ __forceinline__ unsigned short f2bf(float x) {
    __hip_bfloat16 h = __float2bfloat16(x);
    return *reinterpret_cast<unsigned short*>(&h);
}
static __device__ __forceinline__ unsigned short f2h(float x) {
    _Float16 h = (_Float16)x;
    return *reinterpret_cast<unsigned short*>(&h);
}
static __device__ __forceinline__ float q(float x) { return bf2f(f2bf(x)); }

// ---------------------------------------------------------------------------
// Kernel 1: RoPE(y) -> yb bf16; W2 -> W2b f16 [kg96][row272][8] (pad rows 0);
// (big path) W1 -> W1b bf16 [kg96][row1536][8] (row<768 = L-half, >=768 = R).
// R17: transpose mappings ROW-FASTEST -> coalesced 16B stores (proven good).
// ---------------------------------------------------------------------------
__global__ __launch_bounds__(256) void prep_kernel(
    const float* __restrict__ y, const float* __restrict__ W1,
    const float* __restrict__ W2,
    unsigned short* __restrict__ yb, unsigned short* __restrict__ W2b,
    unsigned short* __restrict__ W1b, int do_w1b) {
    int bid = blockIdx.x;
    int t = threadIdx.x;
    if (bid < SDIM) {
        int s = bid;
        for (int p = t; p < HALF; p += 256) {
            float invf = __expf(-(2.0f * (float)p / (float)HDIM) * 9.210340371976184f);
            float th = (float)s * invf;
            float c = cosf(th), sn = sinf(th);
            float y0 = y[s * HDIM + 2 * p], y1 = y[s * HDIM + 2 * p + 1];
            yb[s * HDIM + 2 * p]     = f2bf(y0 * c - y1 * sn);
            yb[s * HDIM + 2 * p + 1] = f2bf(y1 * c + y0 * sn);
        }
    } else if (bid < SDIM + 102) {
        int idx = (bid - SDIM) * 256 + t;       // [0, 96*272)
        if (idx < 96 * OPAD) {
            int kg = idx / OPAD, row = idx - kg * OPAD;  // row fastest
            unsigned short o8[8];
            if (row < ODIM) {
                float4 a = *reinterpret_cast<const float4*>(W2 + row * HDIM + kg * 8);
                float4 b = *reinterpret_cast<const float4*>(W2 + row * HDIM + kg * 8 + 4);
                o8[0] = f2h(a.x); o8[1] = f2h(a.y); o8[2] = f2h(a.z); o8[3] = f2h(a.w);
                o8[4] = f2h(b.x); o8[5] = f2h(b.y); o8[6] = f2h(b.z); o8[7] = f2h(b.w);
            } else {
                #pragma unroll
                for (int e = 0; e < 8; ++e) o8[e] = 0;
            }
            *reinterpret_cast<uint4*>(W2b + ((size_t)kg * OPAD + row) * 8) =
                *reinterpret_cast<uint4*>(o8);
        }
    } else if (do_w1b) {
        int idx = (bid - SDIM - 102) * 256 + t; // [0, 96*1536)
        int kg = idx / 1536, row = idx - kg * 1536;      // row fastest
        const float* src = (row < 768) ? (W1 + row * 1536 + kg * 8)
                                       : (W1 + (row - 768) * 1536 + 768 + kg * 8);
        float4 a = *reinterpret_cast<const float4*>(src);
        float4 b = *reinterpret_cast<const float4*>(src + 4);
        unsigned short o8[8];
        o8[0] = f2bf(a.x); o8[1] = f2bf(a.y); o8[2] = f2bf(a.z); o8[3] = f2bf(a.w);
        o8[4] = f2bf(b.x); o8[5] = f2bf(b.y); o8[6] = f2bf(b.z); o8[7] = f2bf(b.w);
        *reinterpret_cast<uint4*>(W1b + ((size_t)kg * 1536 + row) * 8) =
            *reinterpret_cast<uint4*>(o8);
    }
}

// ---------------------------------------------------------------------------
// Kernel 2 (lr4, R19, proven): barrier-free L/R GEMM from W1b (L2-resident).
// Grid (96,10): one 16-row s-tile per wave, 960 waves (~3.75/CU) -- this
// kernel is latency-bound; wave count is the latency-hiding resource.
// ---------------------------------------------------------------------------
__global__ __launch_bounds__(64, 2) void lr3_kernel(
    const unsigned short* __restrict__ yb, const unsigned short* __restrict__ W1b,
    const float* __restrict__ b1,
    unsigned short* __restrict__ Lb, unsigned short* __restrict__ Rt) {
    int l = threadIdx.x & 63;
    int l16 = l & 15, qd = l >> 4;
    int mt = blockIdx.x;                 // m-tile [0,96)
    int sq = blockIdx.y;                 // s-tile [0,10)
    int s0 = sq * 16 + l16;

    floatx4 acc = (floatx4){0.0f, 0.0f, 0.0f, 0.0f};

    const unsigned short* yrow0 = yb + s0 * HDIM;

    for (int ks = 0; ks < 24; ++ks) {
        int k = ks * 32 + qd * 8;
        int kg = ks * 4 + qd;
        union { uint4 u; short8 s; } bu0, au;
        bu0.u = *reinterpret_cast<const uint4*>(yrow0 + k);
        au.u = *reinterpret_cast<const uint4*>(
            W1b + ((size_t)kg * 1536 + mt * 16 + l16) * 8);
        acc = __builtin_amdgcn_mfma_f32_16x16x32_bf16(
            au.s, bu0.s, acc, 0, 0, 0);
    }

    int o2 = mt * 16 + qd * 4;
    int s_out = sq * 16 + l16;
    unsigned short out4[4];
    if (o2 < 768) {
        #pragma unroll
        for (int r = 0; r < 4; ++r) out4[r] = f2h(acc[r]);
        *reinterpret_cast<uint2*>(Lb + s_out * HDIM + o2) =
            *reinterpret_cast<uint2*>(out4);
    } else {
        int ob = o2 - 768;               // [0,768), aligned to 4
        #pragma unroll
        for (int r = 0; r < 4; ++r)
            out4[r] = f2h(acc[r] + b1[ob + r]);
        // Rt[kg=ob>>3][s][e=ob&7], 4 consecutive e -> uint2 store
        *reinterpret_cast<uint2*>(
            Rt + ((size_t)(ob >> 3) * SDIM + s_out) * 8 + (ob & 7)) =
            *reinterpret_cast<uint2*>(out4);
    }
}

// ---------------------------------------------------------------------------
// Kernel 3 (small-ws path only): pure-VALU L/R (f16; R transposed).
// ---------------------------------------------------------------------------
__global__ __launch_bounds__(256) void lr_fallback_kernel(
    const unsigned short* __restrict__ yb, const float* __restrict__ W1,
    const float* __restrict__ b1,
    unsigned short* __restrict__ Lb, unsigned short* __restrict__ Rt) {
    int idx = blockIdx.x * 256 + threadIdx.x;   // [0, 160*1536)
    int s = idx / 1536;
    int o2 = idx - s * 1536;
    const unsigned short* yrow = yb + s * HDIM;
    if (o2 < 768) {
        const float* wp = W1 + o2 * 1536;
        float a0 = 0.0f;
        for (int k = 0; k < HDIM; ++k) a0 += q(wp[k]) * bf2f(yrow[k]);
        Lb[s * HDIM + o2] = f2h(a0);
    } else {
        int ob = o2 - 768;
        const float* wp = W1 + ob * 1536 + 768;
        float a0 = 0.0f;
        for (int k = 0; k < HDIM; ++k) a0 += q(wp[k]) * bf2f(yrow[k]);
        Rt[((size_t)(ob >> 3) * SDIM + s) * 8 + (ob & 7)] = f2h(a0 + b1[ob]);
    }
}

// ---------------------------------------------------------------------------
// Kernel 4 (R21): DIRECT-GLOBAL f16 pair-GEMM -- no LDS, no barriers.
// WHY (R5 counters, first real main readout): main was 52.7us (3buf) /
// ~38.8us (2buf r14) with MfmaUtil 7.3%, VALUBusy 14%, Occupancy 15%,
// HBM 7%, FETCH 2.8MB -> pure latency/stall-bound; W2b restream is entirely
// L2/L3-served, so LDS staging buys nothing and costs: 12 barriers+drains
// per block, wave-lockstep coupling, and an LDS occupancy cap.
// NOW: A-fragments read straight from W2b (L2-resident; 256B contiguous per
// quad = coalesced). One wave per block, grid (80,5,8) = 3200 independent
// waves (~12.5/CU), free-running like the proven lr3. Same per-wave tile
// (2 i x 16 j x 4-5 m), same loop order, same MFMA accumulation chains,
// same h-build ops, same epilogue -> bit-identical output.
// HISTORY: r15 m-split 125.2 REGR; R18 i-tile-4x 113.3 REGR (cut co-resident
// waves -> latency signature); R20 counted-vmcnt 3-buf 123.4 REGR (LDS cap).
// ---------------------------------------------------------------------------
__global__ __launch_bounds__(64, 4) void main_kernel(
    const unsigned short* __restrict__ Lb, const unsigned short* __restrict__ Rt,
    const unsigned short* __restrict__ W2b,
    const float* __restrict__ b2, float* __restrict__ out) {
    int l = threadIdx.x & 63;
    int l16 = l & 15, qd = l >> 4;
    int w = blockIdx.z;              // 0..7 (was wave id in the 512-block)
    int jh = w & 1;                  // j-half
    int mq = w >> 1;                 // m-quarter
    int mt0 = mq * 4;
    int nmt = (mq == 3) ? 5 : 4;     // m-split 4/4/4/5 (17 tiles)
    int i0 = blockIdx.x * 2;
    int j = blockIdx.y * 32 + jh * 16 + l16;

    floatx4 acc[2][5];
    #pragma unroll
    for (int c = 0; c < 2; ++c)
        #pragma unroll
        for (int mtl = 0; mtl < 5; ++mtl)
            acc[c][mtl] = (floatx4){0.0f, 0.0f, 0.0f, 0.0f};

    const unsigned short* Lrow0 = Lb + i0 * HDIM;
    const unsigned short* Lrow1 = Lb + (i0 + 1) * HDIM;
    // Per-lane W2b base: row = l16 (+ mt*16), kg advances in the loop.
    const unsigned short* wbase = W2b + (size_t)l16 * 8;

    #pragma unroll 2
    for (int kc = 0; kc < 12; ++kc) {
        #pragma unroll
        for (int ks = 0; ks < 2; ++ks) {
            int k = kc * 64 + ks * 32 + qd * 8;
            int kg = kc * 8 + ks * 4 + qd;
            half8 bfrag[2];
            // R read: contiguous across lanes (Rt[kg][j][8])
            union { uint4 u; half8 h; } ru;
            ru.u = *reinterpret_cast<const uint4*>(
                Rt + ((size_t)kg * SDIM + j) * 8);
            #pragma unroll
            for (int c = 0; c < 2; ++c) {
                const unsigned short* Lr = c ? Lrow1 : Lrow0;
                union { uint4 u; half8 h; } lu;
                lu.u = *reinterpret_cast<const uint4*>(Lr + k);
                half8 hv = lu.h + ru.h;          // v_pk_add_f16
                #pragma unroll
                for (int e = 0; e < 8; ++e)      // v_pk_max_f16
                    hv[e] = hv[e] > (_Float16)0.0f ? hv[e] : (_Float16)0.0f;
                bfrag[c] = hv;
            }
            // A-fragments direct from W2b: [kg][mt*16 + l16][8] f16;
            // 16 consecutive rows x 16B per quad = 256B contiguous, L2-hit.
            const unsigned short* wkg = wbase + (size_t)kg * OPAD * 8;
            #pragma unroll
            for (int mtl = 0; mtl < 5; ++mtl) {
                if (mtl < nmt) {
                    union { uint4 u; half8 h; } au;
                    au.u = *reinterpret_cast<const uint4*>(
                        wkg + (size_t)(mt0 + mtl) * 16 * 8);
                    acc[0][mtl] = __builtin_amdgcn_mfma_f32_16x16x32_f16(
                        au.h, bfrag[0], acc[0][mtl], 0, 0, 0);
                    acc[1][mtl] = __builtin_amdgcn_mfma_f32_16x16x32_f16(
                        au.h, bfrag[1], acc[1][mtl], 0, 0, 0);
                }
            }
        }
    }

    #pragma unroll
    for (int c = 0; c < 2; ++c) {
        int i = i0 + c;
        #pragma unroll
        for (int mtl = 0; mtl < 5; ++mtl) {
            if (mtl < nmt) {
                int ob = (mt0 + mtl) * 16 + qd * 4;
                if (ob < ODIM) {
                    float4 bv = *reinterpret_cast<const float4*>(b2 + ob);
                    int rel = ob >> 2;
                    float4 v;
                    v.x = 1.0f / (1.0f + __expf(-(acc[c][mtl][0] + bv.x)));
                    v.y = 1.0f / (1.0f + __expf(-(acc[c][mtl][1] + bv.y)));
                    v.z = 1.0f / (1.0f + __expf(-(acc[c][mtl][2] + bv.z)));
                    v.w = 1.0f / (1.0f + __expf(-(acc[c][mtl][3] + bv.w)));
                    *reinterpret_cast<float4*>(
                        out + (((rel * SDIM) + i) * SDIM + j) * 4) = v;
                }
            }
        }
    }
}

__global__ void ws_too_small_kernel(float* out) { out[0] = 999.0f; }

extern "C" void kernel_launch(void* const* d_in, const int* in_sizes, int n_in,
                              void* d_out, int out_size, void* d_ws, size_t ws_size,
                              hipStream_t stream) {
    const float* y  = (const float*)d_in[0];
    // d_in[1] = event_idx : unused by the reference
    const float* W1 = (const float*)d_in[2];
    const float* b1 = (const float*)d_in[3];
    const float* W2 = (const float*)d_in[4];
    const float* b2 = (const float*)d_in[5];
    float* out = (float*)d_out;

    if (ws_size < (size_t)WS_SMALL) {
        ws_too_small_kernel<<<dim3(1), dim3(1), 0, stream>>>(out);
        return;
    }

    unsigned short* yb  = (unsigned short*)((char*)d_ws + 16);    // 160*768
    unsigned short* Lb  = yb + SDIM * HDIM;
    unsigned short* Rt  = Lb + SDIM * HDIM;                       // 96*160*8
    unsigned short* W2b = Rt + SDIM * HDIM;                       // 96*272*8
    unsigned short* W1b = W2b + 96 * OPAD * 8;                    // 96*1536*8

    if (ws_size >= (size_t)WS_BIG) {
        prep_kernel<<<dim3(SDIM + 102 + 576), dim3(256), 0, stream>>>(
            y, W1, W2, yb, W2b, W1b, 1);
        lr3_kernel<<<dim3(96, 10), dim3(64), 0, stream>>>(yb, W1b, b1, Lb, Rt);
        main_kernel<<<dim3(80, 5, 8), dim3(64), 0, stream>>>(Lb, Rt, W2b, b2, out);
    } else {
        prep_kernel<<<dim3(SDIM + 102), dim3(256), 0, stream>>>(
            y, W1, W2, yb, W2b, W1b, 0);
        lr_fallback_kernel<<<dim3(960), dim3(256), 0, stream>>>(yb, W1, b1, Lb, Rt);
        main_kernel<<<dim3(80, 5, 8), dim3(64), 0, stream>>>(Lb, Rt, W2b, b2, out);
    }
}